// Round 10
// baseline (2096.545 us; speedup 1.0000x reference)
//
#include <hip/hip_runtime.h>
#include <hip/hip_cooperative_groups.h>
#include <hip/hip_bf16.h>

namespace cg = cooperative_groups;

#define T_STEPS 512
#define BATCH   32
#define FDIM    64
#define UDIM    512
#define NWG_DIR 32
#define SENT    0xFFFFFFFFu

typedef __attribute__((ext_vector_type(8))) __bf16 bf16x8;
typedef __attribute__((ext_vector_type(4))) float  f32x4;

// Round-10 = round-9 with the compile fix: __builtin_nontemporal_load needs a
// clang ext-vector pointer (f32x4*), not HIP's float4 struct.
//  (a) nontemporal out-stores + x-loads: stop the 64MB out-stream evicting
//      the 192KB exchange buffers from LLC (FETCH_SIZE 170->215MB r5->r7),
//      keeping sentinel polls at LLC latency.
//  (b) dual MFMA accumulators (even/odd k-subtile): dep chain 18 -> 9.
//
// Exchange protocol (unchanged, proven r7): buffers hold bf16 h pairs per
// dword; 0xFFFFFFFF = "not written" (NaN pair, unproducible by finite gate
// math). Consumers poll (sc0 sc1 asm loads) until their chunks are
// sentinel-free. Triple buffer; poison own slice of buf[(t+2)%3] each step;
// vmcnt(0) before the h store orders poison < h at the LLC.
//
// ws layout (bytes): dir d, buffer b in [0,3): chunk at (d*3+b)*32768,
// each [32 rows][512 bf16 cols] = 32KB. Total 192KB. No flags, no counters.

__global__ __launch_bounds__(512, 2)
void lstm_bidir_kernel(const float* __restrict__ x,
                       const float* __restrict__ Kf, const float* __restrict__ Rf,
                       const float* __restrict__ bfp,
                       const float* __restrict__ Kb, const float* __restrict__ Rb,
                       const float* __restrict__ bbp,
                       float* __restrict__ out, float* __restrict__ ws)
{
    __shared__ __align__(16) unsigned char hsb[BATCH * 1024];      // 32KB bf16 h, swizzled rows
    __shared__ __align__(16) unsigned char xsb[2][BATCH * 128];    // 8KB bf16 x, swizzled rows
    __shared__ __align__(16) float zbuf[BATCH * 68];               // 8.7KB z staging
    __shared__ float cbuf[512];                                    // c state, one per (b, c)
    __shared__ float bsh[64];                                      // bias slice

    const int tid = threadIdx.x;
    const int wg  = blockIdx.x;
    const int dir   = wg >> 5;          // 0 fwd, 1 bwd
    const int slice = wg & 31;
    const int colbase = slice * 16;

    const float* Kg = dir ? Kb : Kf;
    const float* Rg = dir ? Rb : Rf;
    const float* bg = dir ? bbp : bfp;

    unsigned char* wsb = (unsigned char*)ws;
    unsigned char* dirbase = wsb + (size_t)dir * 98304;   // 3 x 32KB buffers

    // ---- init: buf0 = h_0 = 0 (real), buf1/buf2 = SENTINEL; both dirs ----
    {
        int g = wg * 512 + tid;                       // 0..32767
        ((unsigned int*)wsb)[g] = (((g >> 13) % 3) == 0) ? 0u : SENT;
        int g2 = g + 32768;
        if (g2 < 49152)
            ((unsigned int*)wsb)[g2] = (((g2 >> 13) % 3) == 0) ? 0u : SENT;
    }
    if (tid < 64) bsh[tid] = bg[(tid >> 4) * 512 + colbase + (tid & 15)];
    cbuf[tid] = 0.f;

    // ---- B-fragments (R, K slices) into registers, bf16 ----
    const int lane = tid & 63;
    const int w    = tid >> 6;      // wave 0..7
    const int mt   = w >> 2;        // M tile (batch half)
    const int gate = w & 3;         // i,f,g,o
    const int bn   = lane & 15;     // B col within tile
    const int kq   = lane >> 4;     // k quarter 0..3
    const int gcol = gate * 512 + colbase + bn;

    bf16x8 breg[18];
    #pragma unroll
    for (int s = 0; s < 16; ++s) {
        const int k0 = s * 32 + kq * 8;
        bf16x8 v;
        #pragma unroll
        for (int e = 0; e < 8; ++e)
            v[e] = (__bf16)Rg[(size_t)(k0 + e) * 2048 + gcol];
        breg[s] = v;
    }
    #pragma unroll
    for (int s = 0; s < 2; ++s) {
        const int k0 = s * 32 + kq * 8;
        bf16x8 v;
        #pragma unroll
        for (int e = 0; e < 8; ++e)
            v[e] = (__bf16)Kg[(size_t)(k0 + e) * 2048 + gcol];
        breg[16 + s] = v;
    }

    // ---- prefetch x_0 into xsb[0] (bf16, swizzled) ----
    {
        const int t0 = dir ? (T_STEPS - 1) : 0;
        if (tid < 256) {
            int b = tid >> 3, m = tid & 7;
            const float4* xg = (const float4*)(x + (size_t)b * (T_STEPS * FDIM) + (size_t)t0 * FDIM + m * 8);
            float4 v0 = xg[0], v1 = xg[1];
            unsigned int p0 = ((unsigned int)__builtin_bit_cast(unsigned short, (__bf16)v0.x)) |
                              ((unsigned int)__builtin_bit_cast(unsigned short, (__bf16)v0.y) << 16);
            unsigned int p1 = ((unsigned int)__builtin_bit_cast(unsigned short, (__bf16)v0.z)) |
                              ((unsigned int)__builtin_bit_cast(unsigned short, (__bf16)v0.w) << 16);
            unsigned int p2 = ((unsigned int)__builtin_bit_cast(unsigned short, (__bf16)v1.x)) |
                              ((unsigned int)__builtin_bit_cast(unsigned short, (__bf16)v1.y) << 16);
            unsigned int p3 = ((unsigned int)__builtin_bit_cast(unsigned short, (__bf16)v1.z)) |
                              ((unsigned int)__builtin_bit_cast(unsigned short, (__bf16)v1.w) << 16);
            uint4 pk = make_uint4(p0, p1, p2, p3);
            *(uint4*)(xsb[0] + b * 128 + (m ^ (b & 7)) * 16) = pk;
        }
    }

    cg::grid_group grid = cg::this_grid();
    grid.sync();   // one-time: init (zeros + sentinels) visible device-wide

    const int bb = tid >> 4;        // batch row for staging/gates
    const int q  = tid & 15;        // chunk / col-within-slice index
    float h_keep = 0.f;

    #pragma unroll 1
    for (int t = 0; t < T_STEPS; ++t) {
        // ---- A: deferred out store for step t-1, non-temporal (no LLC alloc) ----
        if (t > 0) {
            const int txp = dir ? (T_STEPS - t) : (t - 1);
            float* outp = out + (size_t)bb * (T_STEPS * 2 * UDIM) + (size_t)txp * (2 * UDIM)
                          + dir * UDIM + colbase + q;
            __builtin_nontemporal_store(h_keep, outp);
        }

        // ---- B: x_{t+1} non-temporal loads (held in regs through the poll) ----
        f32x4 xv0 = {0.f, 0.f, 0.f, 0.f};
        f32x4 xv1 = {0.f, 0.f, 0.f, 0.f};
        const bool xload = (t + 1 < T_STEPS) && (tid < 256);
        const int bxr = tid >> 3, mx = tid & 7;
        if (xload) {
            const int tn = dir ? (T_STEPS - 2 - t) : (t + 1);
            const f32x4* xg = (const f32x4*)(x + (size_t)bxr * (T_STEPS * FDIM) + (size_t)tn * FDIM + mx * 8);
            xv0 = __builtin_nontemporal_load(xg);
            xv1 = __builtin_nontemporal_load(xg + 1);
        }

        // ---- C: poll-load own 4 chunks of buf[t%3] until sentinel-free ----
        uint4 r0, r1, r2, r3;
        {
            const unsigned char* srcrow = dirbase + (size_t)(t % 3) * 32768 + bb * 1024;
            for (;;) {
                asm volatile("global_load_dwordx4 %0, %1, off sc0 sc1"
                             : "=&v"(r0) : "v"(srcrow + (q +  0) * 16) : "memory");
                asm volatile("global_load_dwordx4 %0, %1, off sc0 sc1"
                             : "=&v"(r1) : "v"(srcrow + (q + 16) * 16) : "memory");
                asm volatile("global_load_dwordx4 %0, %1, off sc0 sc1"
                             : "=&v"(r2) : "v"(srcrow + (q + 32) * 16) : "memory");
                asm volatile("global_load_dwordx4 %0, %1, off sc0 sc1"
                             : "=&v"(r3) : "v"(srcrow + (q + 48) * 16) : "memory");
                asm volatile("s_waitcnt vmcnt(0)" ::: "memory");
                __builtin_amdgcn_sched_barrier(0);
                unsigned bad = (r0.x == SENT) | (r0.y == SENT) | (r0.z == SENT) | (r0.w == SENT)
                             | (r1.x == SENT) | (r1.y == SENT) | (r1.z == SENT) | (r1.w == SENT)
                             | (r2.x == SENT) | (r2.y == SENT) | (r2.z == SENT) | (r2.w == SENT)
                             | (r3.x == SENT) | (r3.y == SENT) | (r3.z == SENT) | (r3.w == SENT);
                if (!bad) break;   // load RT itself is the poll backoff
            }
        }

        // ---- D: poison own slice of buf[(t+2)%3] (stale h_{t-1}, consumed) ----
        if (tid < 256) {
            int prow = tid >> 3, pd = tid & 7;
            unsigned int* pp = (unsigned int*)(dirbase + (size_t)((t + 2) % 3) * 32768
                                               + prow * 1024 + colbase * 2) + pd;
            __hip_atomic_store(pp, SENT, __ATOMIC_RELAXED, __HIP_MEMORY_SCOPE_AGENT);
        }

        // ---- E: LDS writes: h chunks (swizzled) + x_{t+1} ----
        {
            const int inv = bb & 7;
            unsigned char* hrow = hsb + bb * 1024;
            *(uint4*)(hrow + (((q +  0) ^ inv) << 4)) = r0;
            *(uint4*)(hrow + (((q + 16) ^ inv) << 4)) = r1;
            *(uint4*)(hrow + (((q + 32) ^ inv) << 4)) = r2;
            *(uint4*)(hrow + (((q + 48) ^ inv) << 4)) = r3;
        }
        if (xload) {
            unsigned int p0 = ((unsigned int)__builtin_bit_cast(unsigned short, (__bf16)xv0.x)) |
                              ((unsigned int)__builtin_bit_cast(unsigned short, (__bf16)xv0.y) << 16);
            unsigned int p1 = ((unsigned int)__builtin_bit_cast(unsigned short, (__bf16)xv0.z)) |
                              ((unsigned int)__builtin_bit_cast(unsigned short, (__bf16)xv0.w) << 16);
            unsigned int p2 = ((unsigned int)__builtin_bit_cast(unsigned short, (__bf16)xv1.x)) |
                              ((unsigned int)__builtin_bit_cast(unsigned short, (__bf16)xv1.y) << 16);
            unsigned int p3 = ((unsigned int)__builtin_bit_cast(unsigned short, (__bf16)xv1.z)) |
                              ((unsigned int)__builtin_bit_cast(unsigned short, (__bf16)xv1.w) << 16);
            uint4 pk = make_uint4(p0, p1, p2, p3);
            *(uint4*)(xsb[(t + 1) & 1] + bxr * 128 + ((mx ^ (bxr & 7)) * 16)) = pk;
        }
        __syncthreads();   // F

        // ---- G: MFMA with dual accumulators (dep chain 18 -> 9) ----
        f32x4 acc0 = {0.f, 0.f, 0.f, 0.f};
        f32x4 acc1 = {0.f, 0.f, 0.f, 0.f};
        {
            const int arow = mt * 16 + bn;               // batch row (A row)
            const int inv  = arow & 7;
            const unsigned char* hrowA = hsb + arow * 1024;
            #pragma unroll
            for (int s = 0; s < 8; ++s) {
                int m0 = (2 * s)     * 4 + kq;
                int m1 = (2 * s + 1) * 4 + kq;
                bf16x8 a0 = *(const bf16x8*)(hrowA + ((m0 ^ inv) * 16));
                bf16x8 a1 = *(const bf16x8*)(hrowA + ((m1 ^ inv) * 16));
                acc0 = __builtin_amdgcn_mfma_f32_16x16x32_bf16(a0, breg[2 * s],     acc0, 0, 0, 0);
                acc1 = __builtin_amdgcn_mfma_f32_16x16x32_bf16(a1, breg[2 * s + 1], acc1, 0, 0, 0);
            }
            const unsigned char* xrowA = xsb[t & 1] + arow * 128;
            {
                int m0 = 0 * 4 + kq, m1 = 1 * 4 + kq;
                bf16x8 a0 = *(const bf16x8*)(xrowA + ((m0 ^ inv) * 16));
                bf16x8 a1 = *(const bf16x8*)(xrowA + ((m1 ^ inv) * 16));
                acc0 = __builtin_amdgcn_mfma_f32_16x16x32_bf16(a0, breg[16], acc0, 0, 0, 0);
                acc1 = __builtin_amdgcn_mfma_f32_16x16x32_bf16(a1, breg[17], acc1, 0, 0, 0);
            }
            // D layout: col = lane&15, row = (lane>>4)*4 + reg
            const int zb = mt * 16 + kq * 4;
            #pragma unroll
            for (int j = 0; j < 4; ++j)
                zbuf[(zb + j) * 68 + gate * 16 + bn] = acc0[j] + acc1[j];
        }
        __syncthreads();   // H

        // ---- I: gates + J: ordered h store ----
        {
            const float* zr = zbuf + bb * 68 + q;
            float zi = zr[0]  + bsh[q];
            float zf = zr[16] + bsh[16 + q];
            float zg = zr[32] + bsh[32 + q];
            float zo = zr[48] + bsh[48 + q];
            float gi = 1.f / (1.f + __expf(-zi));
            float gf = 1.f / (1.f + __expf(-zf));
            float gg = zg / (1.f + __expf(-zg));         // swish
            float go = 1.f / (1.f + __expf(-zo));
            float cv = gf * cbuf[tid] + gi * gg;
            cbuf[tid] = cv;
            float h  = go * (cv / (1.f + __expf(-cv)));  // o * swish(c)
            h_keep = h;                                   // out store deferred

            // pack bf16 pair via shfl; even-q lanes store one dword
            unsigned short hu = __builtin_bit_cast(unsigned short, (__bf16)h);
            int other = __shfl_xor((int)hu, 1);
            // J: ensure this wave's poison stores are at the LLC BEFORE h lands
            asm volatile("s_waitcnt vmcnt(0)" ::: "memory");
            if ((q & 1) == 0) {
                unsigned int packed = (unsigned int)hu | ((unsigned int)(unsigned short)other << 16);
                unsigned int* dst = (unsigned int*)(dirbase + (size_t)((t + 1) % 3) * 32768)
                                    + bb * 256 + ((colbase + q) >> 1);
                __hip_atomic_store(dst, packed, __ATOMIC_RELAXED, __HIP_MEMORY_SCOPE_AGENT);
            }
        }
        // no trailing barrier: next iter's LDS writes can't collide
        // (hsb/xsb writers passed H; zbuf next written only after F(t+1))
    }

    // final out store (t = T_STEPS-1), non-temporal
    {
        const int txl = dir ? 0 : (T_STEPS - 1);
        float* outp = out + (size_t)bb * (T_STEPS * 2 * UDIM) + (size_t)txl * (2 * UDIM)
                      + dir * UDIM + colbase + q;
        __builtin_nontemporal_store(h_keep, outp);
    }
}

extern "C" void kernel_launch(void* const* d_in, const int* in_sizes, int n_in,
                              void* d_out, int out_size, void* d_ws, size_t ws_size,
                              hipStream_t stream) {
    (void)in_sizes; (void)n_in; (void)out_size; (void)ws_size;
    const float* x  = (const float*)d_in[0];
    const float* Kf = (const float*)d_in[1];
    const float* Rf = (const float*)d_in[2];
    const float* bf = (const float*)d_in[3];
    const float* Kb = (const float*)d_in[4];
    const float* Rb = (const float*)d_in[5];
    const float* bb = (const float*)d_in[6];
    float* out = (float*)d_out;
    float* ws  = (float*)d_ws;

    void* args[] = {&x, &Kf, &Rf, &bf, &Kb, &Rb, &bb, &out, &ws};
    hipLaunchCooperativeKernel((const void*)lstm_bidir_kernel,
                               dim3(64), dim3(512), args, 0, stream);
}

// Round 11
// 2095.920 us; speedup vs baseline: 1.0003x; 1.0003x over previous
//
#include <hip/hip_runtime.h>
#include <hip/hip_cooperative_groups.h>
#include <hip/hip_bf16.h>

namespace cg = cooperative_groups;

#define T_STEPS 512
#define BATCH   32
#define FDIM    64
#define UDIM    512
#define NWG     32
#define SENT    0xFFFFFFFFu

typedef __attribute__((ext_vector_type(8))) __bf16 bf16x8;
typedef __attribute__((ext_vector_type(4))) float  f32x4;

// Round-11: direction-merged WGs. 32 WGs; each owns 16 h-cols of BOTH
// directions and alternates fwd-half / bwd-half per iteration. While one
// direction's half computes (~1us), the other direction's h (stored last
// iteration) commits to LLC -> its sentinel poll hits on the first try.
// Exchange latency is hidden under compute; only the 32KB bulk pull remains.
// nt cache hints from r10 REVERTED (they forced partial-line HBM RMW:
// FETCH +62MB, dur +44%). Dual MFMA accumulators kept (proven r10).
//
// Exchange protocol per direction (proven r7): bf16 h pairs per dword;
// 0xFFFFFFFF = "not written". Poll (sc0 sc1) until own chunks sentinel-free.
// Triple buffer; poison own slice of buf[(t+2)%3]; vmcnt(0) before the h
// store orders poison < h at the LLC.
//
// ws layout (bytes): dir d buffer b: (d*3+b)*32768, each [32 rows][512 bf16].
// Total 192KB. hsb LDS is REUSED across the two halves (H-barrier protects).

__global__ __launch_bounds__(512, 1)
void lstm_bidir_kernel(const float* __restrict__ x,
                       const float* __restrict__ Kf, const float* __restrict__ Rf,
                       const float* __restrict__ bfp,
                       const float* __restrict__ Kb, const float* __restrict__ Rb,
                       const float* __restrict__ bbp,
                       float* __restrict__ out, float* __restrict__ ws)
{
    __shared__ __align__(16) unsigned char hsb[BATCH * 1024];        // 32KB, shared by both halves
    __shared__ __align__(16) unsigned char xsb[2][2][BATCH * 128];   // 16KB [dir][parity]
    __shared__ __align__(16) float zbuf[BATCH * 68];                 // 8.7KB
    __shared__ float cbuf[2][512];                                   // c state per dir
    __shared__ float bsh[2][64];                                     // bias per dir

    const int tid = threadIdx.x;
    const int wg  = blockIdx.x;          // 0..31 = slice
    const int colbase = wg * 16;

    const float* Kgs[2] = {Kf, Kb};
    const float* Rgs[2] = {Rf, Rb};
    const float* bgs[2] = {bfp, bbp};

    unsigned char* wsb = (unsigned char*)ws;

    // ---- init: buf0 = h_0 = 0, buf1/buf2 = SENTINEL; both dirs (49152 dwords) ----
    {
        int g = wg * 512 + tid;                        // 0..16383
        #pragma unroll
        for (int r = 0; r < 3; ++r) {
            int gg = g + r * 16384;                    // covers 0..49151
            ((unsigned int*)wsb)[gg] = (((gg >> 13) % 3) == 0) ? 0u : SENT;
        }
    }
    if (tid < 128) bsh[tid >> 6][tid & 63] =
        bgs[tid >> 6][((tid & 63) >> 4) * 512 + colbase + (tid & 15)];
    cbuf[0][tid] = 0.f;
    cbuf[1][tid] = 0.f;

    // ---- B-fragments (R, K slices) into registers, bf16, BOTH dirs ----
    const int lane = tid & 63;
    const int w    = tid >> 6;      // wave 0..7
    const int mt   = w >> 2;        // M tile (batch half)
    const int gate = w & 3;         // i,f,g,o
    const int bn   = lane & 15;     // B col within tile
    const int kq   = lane >> 4;     // k quarter 0..3
    const int gcol = gate * 512 + colbase + bn;

    bf16x8 breg[2][18];
    #pragma unroll
    for (int d = 0; d < 2; ++d) {
        #pragma unroll
        for (int s = 0; s < 16; ++s) {
            const int k0 = s * 32 + kq * 8;
            bf16x8 v;
            #pragma unroll
            for (int e = 0; e < 8; ++e)
                v[e] = (__bf16)Rgs[d][(size_t)(k0 + e) * 2048 + gcol];
            breg[d][s] = v;
        }
        #pragma unroll
        for (int s = 0; s < 2; ++s) {
            const int k0 = s * 32 + kq * 8;
            bf16x8 v;
            #pragma unroll
            for (int e = 0; e < 8; ++e)
                v[e] = (__bf16)Kgs[d][(size_t)(k0 + e) * 2048 + gcol];
            breg[d][16 + s] = v;
        }
    }

    // ---- prefetch x_0 (fwd: t=0, bwd: t=T-1) into xsb[d][0] ----
    if (tid < 256) {
        int b = tid >> 3, m = tid & 7;
        #pragma unroll
        for (int d = 0; d < 2; ++d) {
            const int t0 = d ? (T_STEPS - 1) : 0;
            const float4* xg = (const float4*)(x + (size_t)b * (T_STEPS * FDIM) + (size_t)t0 * FDIM + m * 8);
            float4 v0 = xg[0], v1 = xg[1];
            unsigned int p0 = ((unsigned int)__builtin_bit_cast(unsigned short, (__bf16)v0.x)) |
                              ((unsigned int)__builtin_bit_cast(unsigned short, (__bf16)v0.y) << 16);
            unsigned int p1 = ((unsigned int)__builtin_bit_cast(unsigned short, (__bf16)v0.z)) |
                              ((unsigned int)__builtin_bit_cast(unsigned short, (__bf16)v0.w) << 16);
            unsigned int p2 = ((unsigned int)__builtin_bit_cast(unsigned short, (__bf16)v1.x)) |
                              ((unsigned int)__builtin_bit_cast(unsigned short, (__bf16)v1.y) << 16);
            unsigned int p3 = ((unsigned int)__builtin_bit_cast(unsigned short, (__bf16)v1.z)) |
                              ((unsigned int)__builtin_bit_cast(unsigned short, (__bf16)v1.w) << 16);
            uint4 pk = make_uint4(p0, p1, p2, p3);
            *(uint4*)(xsb[d][0] + b * 128 + (m ^ (b & 7)) * 16) = pk;
        }
    }

    cg::grid_group grid = cg::this_grid();
    grid.sync();   // one-time: init visible device-wide

    const int bb = tid >> 4;        // batch row for staging/gates
    const int q  = tid & 15;        // chunk / col-within-slice index
    float h_keep[2] = {0.f, 0.f};

    #pragma unroll 1
    for (int t = 0; t < T_STEPS; ++t) {
        #pragma unroll
        for (int d = 0; d < 2; ++d) {
            unsigned char* exbase = wsb + (size_t)d * 98304;

            // ---- A: deferred out store for step t-1 (cached; LLC write-combines) ----
            if (t > 0) {
                const int txp = d ? (T_STEPS - t) : (t - 1);
                out[(size_t)bb * (T_STEPS * 2 * UDIM) + (size_t)txp * (2 * UDIM)
                    + d * UDIM + colbase + q] = h_keep[d];
            }

            // ---- B: x_{t+1} loads (held in regs through the poll) ----
            float4 xv0, xv1;
            const bool xload = (t + 1 < T_STEPS) && (tid < 256);
            const int bxr = tid >> 3, mx = tid & 7;
            if (xload) {
                const int tn = d ? (T_STEPS - 2 - t) : (t + 1);
                const float4* xg = (const float4*)(x + (size_t)bxr * (T_STEPS * FDIM) + (size_t)tn * FDIM + mx * 8);
                xv0 = xg[0]; xv1 = xg[1];
            }

            // ---- C: poll-load own 4 chunks of buf[t%3] until sentinel-free ----
            uint4 r0, r1, r2, r3;
            {
                const unsigned char* srcrow = exbase + (size_t)(t % 3) * 32768 + bb * 1024;
                for (;;) {
                    asm volatile("global_load_dwordx4 %0, %1, off sc0 sc1"
                                 : "=&v"(r0) : "v"(srcrow + (q +  0) * 16) : "memory");
                    asm volatile("global_load_dwordx4 %0, %1, off sc0 sc1"
                                 : "=&v"(r1) : "v"(srcrow + (q + 16) * 16) : "memory");
                    asm volatile("global_load_dwordx4 %0, %1, off sc0 sc1"
                                 : "=&v"(r2) : "v"(srcrow + (q + 32) * 16) : "memory");
                    asm volatile("global_load_dwordx4 %0, %1, off sc0 sc1"
                                 : "=&v"(r3) : "v"(srcrow + (q + 48) * 16) : "memory");
                    asm volatile("s_waitcnt vmcnt(0)" ::: "memory");
                    __builtin_amdgcn_sched_barrier(0);
                    unsigned bad = (r0.x == SENT) | (r0.y == SENT) | (r0.z == SENT) | (r0.w == SENT)
                                 | (r1.x == SENT) | (r1.y == SENT) | (r1.z == SENT) | (r1.w == SENT)
                                 | (r2.x == SENT) | (r2.y == SENT) | (r2.z == SENT) | (r2.w == SENT)
                                 | (r3.x == SENT) | (r3.y == SENT) | (r3.z == SENT) | (r3.w == SENT);
                    if (!bad) break;
                }
            }

            // ---- D: poison own slice of buf[(t+2)%3] (consumed h_{t-1}) ----
            if (tid < 256) {
                int prow = tid >> 3, pd = tid & 7;
                unsigned int* pp = (unsigned int*)(exbase + (size_t)((t + 2) % 3) * 32768
                                                   + prow * 1024 + colbase * 2) + pd;
                __hip_atomic_store(pp, SENT, __ATOMIC_RELAXED, __HIP_MEMORY_SCOPE_AGENT);
            }

            // ---- E: LDS writes: h chunks (swizzled) + x_{t+1} ----
            {
                const int inv = bb & 7;
                unsigned char* hrow = hsb + bb * 1024;
                *(uint4*)(hrow + (((q +  0) ^ inv) << 4)) = r0;
                *(uint4*)(hrow + (((q + 16) ^ inv) << 4)) = r1;
                *(uint4*)(hrow + (((q + 32) ^ inv) << 4)) = r2;
                *(uint4*)(hrow + (((q + 48) ^ inv) << 4)) = r3;
            }
            if (xload) {
                unsigned int p0 = ((unsigned int)__builtin_bit_cast(unsigned short, (__bf16)xv0.x)) |
                                  ((unsigned int)__builtin_bit_cast(unsigned short, (__bf16)xv0.y) << 16);
                unsigned int p1 = ((unsigned int)__builtin_bit_cast(unsigned short, (__bf16)xv0.z)) |
                                  ((unsigned int)__builtin_bit_cast(unsigned short, (__bf16)xv0.w) << 16);
                unsigned int p2 = ((unsigned int)__builtin_bit_cast(unsigned short, (__bf16)xv1.x)) |
                                  ((unsigned int)__builtin_bit_cast(unsigned short, (__bf16)xv1.y) << 16);
                unsigned int p3 = ((unsigned int)__builtin_bit_cast(unsigned short, (__bf16)xv1.z)) |
                                  ((unsigned int)__builtin_bit_cast(unsigned short, (__bf16)xv1.w) << 16);
                uint4 pk = make_uint4(p0, p1, p2, p3);
                *(uint4*)(xsb[d][(t + 1) & 1] + bxr * 128 + ((mx ^ (bxr & 7)) * 16)) = pk;
            }
            __syncthreads();   // F

            // ---- G: MFMA, dual accumulators ----
            f32x4 acc0 = {0.f, 0.f, 0.f, 0.f};
            f32x4 acc1 = {0.f, 0.f, 0.f, 0.f};
            {
                const int arow = mt * 16 + bn;
                const int inv  = arow & 7;
                const unsigned char* hrowA = hsb + arow * 1024;
                #pragma unroll
                for (int s = 0; s < 8; ++s) {
                    int m0 = (2 * s)     * 4 + kq;
                    int m1 = (2 * s + 1) * 4 + kq;
                    bf16x8 a0 = *(const bf16x8*)(hrowA + ((m0 ^ inv) * 16));
                    bf16x8 a1 = *(const bf16x8*)(hrowA + ((m1 ^ inv) * 16));
                    acc0 = __builtin_amdgcn_mfma_f32_16x16x32_bf16(a0, breg[d][2 * s],     acc0, 0, 0, 0);
                    acc1 = __builtin_amdgcn_mfma_f32_16x16x32_bf16(a1, breg[d][2 * s + 1], acc1, 0, 0, 0);
                }
                const unsigned char* xrowA = xsb[d][t & 1] + arow * 128;
                {
                    int m0 = 0 * 4 + kq, m1 = 1 * 4 + kq;
                    bf16x8 a0 = *(const bf16x8*)(xrowA + ((m0 ^ inv) * 16));
                    bf16x8 a1 = *(const bf16x8*)(xrowA + ((m1 ^ inv) * 16));
                    acc0 = __builtin_amdgcn_mfma_f32_16x16x32_bf16(a0, breg[d][16], acc0, 0, 0, 0);
                    acc1 = __builtin_amdgcn_mfma_f32_16x16x32_bf16(a1, breg[d][17], acc1, 0, 0, 0);
                }
                const int zb = mt * 16 + kq * 4;
                #pragma unroll
                for (int j = 0; j < 4; ++j)
                    zbuf[(zb + j) * 68 + gate * 16 + bn] = acc0[j] + acc1[j];
            }
            __syncthreads();   // H

            // ---- I: gates + J: ordered h store ----
            {
                const float* zr = zbuf + bb * 68 + q;
                float zi = zr[0]  + bsh[d][q];
                float zf = zr[16] + bsh[d][16 + q];
                float zg = zr[32] + bsh[d][32 + q];
                float zo = zr[48] + bsh[d][48 + q];
                float gi = 1.f / (1.f + __expf(-zi));
                float gf = 1.f / (1.f + __expf(-zf));
                float gg = zg / (1.f + __expf(-zg));         // swish
                float go = 1.f / (1.f + __expf(-zo));
                float cv = gf * cbuf[d][tid] + gi * gg;
                cbuf[d][tid] = cv;
                float h  = go * (cv / (1.f + __expf(-cv)));  // o * swish(c)
                h_keep[d] = h;

                unsigned short hu = __builtin_bit_cast(unsigned short, (__bf16)h);
                int other = __shfl_xor((int)hu, 1);
                // J: poison stores must reach LLC before h lands
                asm volatile("s_waitcnt vmcnt(0)" ::: "memory");
                if ((q & 1) == 0) {
                    unsigned int packed = (unsigned int)hu | ((unsigned int)(unsigned short)other << 16);
                    unsigned int* dst = (unsigned int*)(exbase + (size_t)((t + 1) % 3) * 32768)
                                        + bb * 256 + ((colbase + q) >> 1);
                    __hip_atomic_store(dst, packed, __ATOMIC_RELAXED, __HIP_MEMORY_SCOPE_AGENT);
                }
            }
            // no trailing barrier (poll of next half/iteration gates hsb reuse;
            // zbuf next written only after the next F)
        }
    }

    // final out stores (t = T_STEPS-1)
    #pragma unroll
    for (int d = 0; d < 2; ++d) {
        const int txl = d ? 0 : (T_STEPS - 1);
        out[(size_t)bb * (T_STEPS * 2 * UDIM) + (size_t)txl * (2 * UDIM)
            + d * UDIM + colbase + q] = h_keep[d];
    }
}

extern "C" void kernel_launch(void* const* d_in, const int* in_sizes, int n_in,
                              void* d_out, int out_size, void* d_ws, size_t ws_size,
                              hipStream_t stream) {
    (void)in_sizes; (void)n_in; (void)out_size; (void)ws_size;
    const float* x  = (const float*)d_in[0];
    const float* Kf = (const float*)d_in[1];
    const float* Rf = (const float*)d_in[2];
    const float* bf = (const float*)d_in[3];
    const float* Kb = (const float*)d_in[4];
    const float* Rb = (const float*)d_in[5];
    const float* bb = (const float*)d_in[6];
    float* out = (float*)d_out;
    float* ws  = (float*)d_ws;

    void* args[] = {&x, &Kf, &Rf, &bf, &Kb, &Rb, &bb, &out, &ws};
    hipLaunchCooperativeKernel((const void*)lstm_bidir_kernel,
                               dim3(NWG), dim3(512), args, 0, stream);
}

// Round 12
// 1455.629 us; speedup vs baseline: 1.4403x; 1.4399x over previous
//
#include <hip/hip_runtime.h>
#include <hip/hip_cooperative_groups.h>
#include <hip/hip_bf16.h>

namespace cg = cooperative_groups;

#define T_STEPS 512
#define BATCH   32
#define FDIM    64
#define UDIM    512
#define NWG_DIR 32
#define SENT    0xFFFFFFFFu

typedef __attribute__((ext_vector_type(8)))  __bf16 bf16x8;
typedef __attribute__((ext_vector_type(4)))  float  f32x4;
typedef __attribute__((ext_vector_type(16))) float  f32x16;

// Round-12 = round-7 base (64 WGs = 2dir x 32 slices, sentinel-poll triple
// buffer, PASS 1453us) with the MFMA restructured to 32x32x16 K-split:
//   wave w = (nt = w>>2, kq = w&3): output cols [nt*32, nt*32+32) of the
//   64 gate-cols, K-quarter kq (128 R-k + 16 x-k). M=32 = full batch.
//   Per-wave A-fragment LDS reads drop 18KB -> 9KB (144KB -> 72KB per WG
//   per step; G-phase was the largest controllable term ~0.48us).
//   B-frags (R,K slices) still resident in registers (9 x bf16x8 = 36 VGPR).
//   zbuf gains a kq dimension: [8 waves][32 rows][33 pad] f32 partials,
//   summed during the gate phase (16 extra LDS dword reads/thread).
// Also: out store moved AFTER the poll (its HBM ack drains under MFMA
// instead of inside the poll's first vmcnt(0)).
// Exchange protocol unchanged (proven r7): bf16 h pairs per dword;
// 0xFFFFFFFF = "not written"; poll sc0 sc1 until sentinel-free; triple
// buffer; poison buf[(t+2)%3]; vmcnt(0) before h store orders poison < h.
//
// MFMA 32x32x16 layouts (cdna4_isa / m74-m101):
//   A: row = lane&31, k = (lane>>5)*8 + e   (bf16x8, 4 VGPR)
//   B: col = lane&31, k = (lane>>5)*8 + e
//   C/D: col = lane&31, row = (r&3) + 8*(r>>2) + 4*(lane>>5), r in [0,16)

__global__ __launch_bounds__(512, 2)
void lstm_bidir_kernel(const float* __restrict__ x,
                       const float* __restrict__ Kf, const float* __restrict__ Rf,
                       const float* __restrict__ bfp,
                       const float* __restrict__ Kb, const float* __restrict__ Rb,
                       const float* __restrict__ bbp,
                       float* __restrict__ out, float* __restrict__ ws)
{
    __shared__ __align__(16) unsigned char hsb[BATCH * 1024];      // 32KB bf16 h, swizzled rows
    __shared__ __align__(16) unsigned char xsb[2][BATCH * 128];    // 8KB bf16 x, swizzled rows
    __shared__ __align__(16) float zbuf[8 * 32 * 33];              // 33.8KB kq-partials
    __shared__ float cbuf[512];                                    // c state, one per (b, c)
    __shared__ float bsh[64];                                      // bias slice

    const int tid = threadIdx.x;
    const int wg  = blockIdx.x;
    const int dir   = wg >> 5;          // 0 fwd, 1 bwd
    const int slice = wg & 31;
    const int colbase = slice * 16;

    const float* Kg = dir ? Kb : Kf;
    const float* Rg = dir ? Rb : Rf;
    const float* bg = dir ? bbp : bfp;

    unsigned char* wsb = (unsigned char*)ws;
    unsigned char* dirbase = wsb + (size_t)dir * 98304;   // 3 x 32KB buffers

    // ---- init: buf0 = h_0 = 0 (real), buf1/buf2 = SENTINEL; both dirs ----
    {
        int g = wg * 512 + tid;                       // 0..32767
        ((unsigned int*)wsb)[g] = (((g >> 13) % 3) == 0) ? 0u : SENT;
        int g2 = g + 32768;
        if (g2 < 49152)
            ((unsigned int*)wsb)[g2] = (((g2 >> 13) % 3) == 0) ? 0u : SENT;
    }
    if (tid < 64) bsh[tid] = bg[(tid >> 4) * 512 + colbase + (tid & 15)];
    cbuf[tid] = 0.f;

    // ---- wave roles & B-fragments (R, K slices) into registers ----
    const int lane = tid & 63;
    const int w    = tid >> 6;      // wave 0..7
    const int nt   = w >> 2;        // col tile (32 cols) 0..1
    const int kq   = w & 3;         // K quarter 0..3
    const int lrow = lane & 31;     // A row / B col
    const int lhi  = lane >> 5;     // k half within K=16
    const int c_local = nt * 32 + lrow;           // 0..63 within gate-block
    const int gcol = (c_local >> 4) * 512 + colbase + (c_local & 15);

    bf16x8 breg[9];
    #pragma unroll
    for (int s = 0; s < 8; ++s) {
        const int k0 = kq * 128 + s * 16 + lhi * 8;
        bf16x8 v;
        #pragma unroll
        for (int e = 0; e < 8; ++e)
            v[e] = (__bf16)Rg[(size_t)(k0 + e) * 2048 + gcol];
        breg[s] = v;
    }
    {
        const int k0 = kq * 16 + lhi * 8;
        bf16x8 v;
        #pragma unroll
        for (int e = 0; e < 8; ++e)
            v[e] = (__bf16)Kg[(size_t)(k0 + e) * 2048 + gcol];
        breg[8] = v;
    }

    // ---- prefetch x_0 into xsb[0] (bf16, swizzled) ----
    {
        const int t0 = dir ? (T_STEPS - 1) : 0;
        if (tid < 256) {
            int b = tid >> 3, m = tid & 7;
            const float4* xg = (const float4*)(x + (size_t)b * (T_STEPS * FDIM) + (size_t)t0 * FDIM + m * 8);
            float4 v0 = xg[0], v1 = xg[1];
            unsigned int p0 = ((unsigned int)__builtin_bit_cast(unsigned short, (__bf16)v0.x)) |
                              ((unsigned int)__builtin_bit_cast(unsigned short, (__bf16)v0.y) << 16);
            unsigned int p1 = ((unsigned int)__builtin_bit_cast(unsigned short, (__bf16)v0.z)) |
                              ((unsigned int)__builtin_bit_cast(unsigned short, (__bf16)v0.w) << 16);
            unsigned int p2 = ((unsigned int)__builtin_bit_cast(unsigned short, (__bf16)v1.x)) |
                              ((unsigned int)__builtin_bit_cast(unsigned short, (__bf16)v1.y) << 16);
            unsigned int p3 = ((unsigned int)__builtin_bit_cast(unsigned short, (__bf16)v1.z)) |
                              ((unsigned int)__builtin_bit_cast(unsigned short, (__bf16)v1.w) << 16);
            uint4 pk = make_uint4(p0, p1, p2, p3);
            *(uint4*)(xsb[0] + b * 128 + (m ^ (b & 7)) * 16) = pk;
        }
    }

    cg::grid_group grid = cg::this_grid();
    grid.sync();   // one-time: init (zeros + sentinels) visible device-wide

    const int bb = tid >> 4;        // batch row for staging/gates
    const int q  = tid & 15;        // chunk / col-within-slice index
    float h_keep = 0.f;

    #pragma unroll 1
    for (int t = 0; t < T_STEPS; ++t) {
        // ---- B: x_{t+1} loads (held in regs through the poll) ----
        float4 xv0, xv1;
        const bool xload = (t + 1 < T_STEPS) && (tid < 256);
        const int bxr = tid >> 3, mx = tid & 7;
        if (xload) {
            const int tn = dir ? (T_STEPS - 2 - t) : (t + 1);
            const float4* xg = (const float4*)(x + (size_t)bxr * (T_STEPS * FDIM) + (size_t)tn * FDIM + mx * 8);
            xv0 = xg[0]; xv1 = xg[1];
        }

        // ---- C: poll-load own 4 chunks of buf[t%3] until sentinel-free ----
        uint4 r0, r1, r2, r3;
        {
            const unsigned char* srcrow = dirbase + (size_t)(t % 3) * 32768 + bb * 1024;
            for (;;) {
                asm volatile("global_load_dwordx4 %0, %1, off sc0 sc1"
                             : "=&v"(r0) : "v"(srcrow + (q +  0) * 16) : "memory");
                asm volatile("global_load_dwordx4 %0, %1, off sc0 sc1"
                             : "=&v"(r1) : "v"(srcrow + (q + 16) * 16) : "memory");
                asm volatile("global_load_dwordx4 %0, %1, off sc0 sc1"
                             : "=&v"(r2) : "v"(srcrow + (q + 32) * 16) : "memory");
                asm volatile("global_load_dwordx4 %0, %1, off sc0 sc1"
                             : "=&v"(r3) : "v"(srcrow + (q + 48) * 16) : "memory");
                asm volatile("s_waitcnt vmcnt(0)" ::: "memory");
                __builtin_amdgcn_sched_barrier(0);
                unsigned bad = (r0.x == SENT) | (r0.y == SENT) | (r0.z == SENT) | (r0.w == SENT)
                             | (r1.x == SENT) | (r1.y == SENT) | (r1.z == SENT) | (r1.w == SENT)
                             | (r2.x == SENT) | (r2.y == SENT) | (r2.z == SENT) | (r2.w == SENT)
                             | (r3.x == SENT) | (r3.y == SENT) | (r3.z == SENT) | (r3.w == SENT);
                if (!bad) break;   // load RT itself is the poll backoff
            }
        }

        // ---- A': deferred out store for t-1 (ack drains under G-phase) ----
        if (t > 0) {
            const int txp = dir ? (T_STEPS - t) : (t - 1);
            out[(size_t)bb * (T_STEPS * 2 * UDIM) + (size_t)txp * (2 * UDIM)
                + dir * UDIM + colbase + q] = h_keep;
        }

        // ---- D: poison own slice of buf[(t+2)%3] (stale h_{t-1}, consumed) ----
        if (tid < 256) {
            int prow = tid >> 3, pd = tid & 7;
            unsigned int* pp = (unsigned int*)(dirbase + (size_t)((t + 2) % 3) * 32768
                                               + prow * 1024 + colbase * 2) + pd;
            __hip_atomic_store(pp, SENT, __ATOMIC_RELAXED, __HIP_MEMORY_SCOPE_AGENT);
        }

        // ---- E: LDS writes: h chunks (swizzled) + x_{t+1} ----
        {
            const int inv = bb & 7;
            unsigned char* hrow = hsb + bb * 1024;
            *(uint4*)(hrow + (((q +  0) ^ inv) << 4)) = r0;
            *(uint4*)(hrow + (((q + 16) ^ inv) << 4)) = r1;
            *(uint4*)(hrow + (((q + 32) ^ inv) << 4)) = r2;
            *(uint4*)(hrow + (((q + 48) ^ inv) << 4)) = r3;
        }
        if (xload) {
            unsigned int p0 = ((unsigned int)__builtin_bit_cast(unsigned short, (__bf16)xv0.x)) |
                              ((unsigned int)__builtin_bit_cast(unsigned short, (__bf16)xv0.y) << 16);
            unsigned int p1 = ((unsigned int)__builtin_bit_cast(unsigned short, (__bf16)xv0.z)) |
                              ((unsigned int)__builtin_bit_cast(unsigned short, (__bf16)xv0.w) << 16);
            unsigned int p2 = ((unsigned int)__builtin_bit_cast(unsigned short, (__bf16)xv1.x)) |
                              ((unsigned int)__builtin_bit_cast(unsigned short, (__bf16)xv1.y) << 16);
            unsigned int p3 = ((unsigned int)__builtin_bit_cast(unsigned short, (__bf16)xv1.z)) |
                              ((unsigned int)__builtin_bit_cast(unsigned short, (__bf16)xv1.w) << 16);
            uint4 pk = make_uint4(p0, p1, p2, p3);
            *(uint4*)(xsb[(t + 1) & 1] + bxr * 128 + ((mx ^ (bxr & 7)) * 16)) = pk;
        }
        __syncthreads();   // F

        // ---- G: 32x32x16 MFMA, K-quarter kq, col-tile nt ----
        {
            f32x16 acc = {0.f,0.f,0.f,0.f,0.f,0.f,0.f,0.f,
                          0.f,0.f,0.f,0.f,0.f,0.f,0.f,0.f};
            const int inv = lrow & 7;
            const unsigned char* hrowA = hsb + lrow * 1024;
            #pragma unroll
            for (int s = 0; s < 8; ++s) {
                int m = kq * 16 + s * 2 + lhi;
                bf16x8 a = *(const bf16x8*)(hrowA + ((m ^ inv) << 4));
                acc = __builtin_amdgcn_mfma_f32_32x32x16_bf16(a, breg[s], acc, 0, 0, 0);
            }
            {
                const unsigned char* xrowA = xsb[t & 1] + lrow * 128;
                int mxc = kq * 2 + lhi;
                bf16x8 ax = *(const bf16x8*)(xrowA + ((mxc ^ inv) << 4));
                acc = __builtin_amdgcn_mfma_f32_32x32x16_bf16(ax, breg[8], acc, 0, 0, 0);
            }
            // D layout: col = lane&31, row = (r&3) + 8*(r>>2) + 4*lhi
            #pragma unroll
            for (int r = 0; r < 16; ++r) {
                int row = (r & 3) + ((r >> 2) << 3) + (lhi << 2);
                zbuf[(w * 32 + row) * 33 + lrow] = acc[r];
            }
        }
        __syncthreads();   // H

        // ---- I: gates (sum kq partials) + J: ordered h store ----
        {
            float zg4[4];
            #pragma unroll
            for (int g = 0; g < 4; ++g) {
                const int cl  = g * 16 + q;
                const int ntg = cl >> 5;
                const int col = cl & 31;
                float s = 0.f;
                #pragma unroll
                for (int k2 = 0; k2 < 4; ++k2)
                    s += zbuf[((ntg * 4 + k2) * 32 + bb) * 33 + col];
                zg4[g] = s + bsh[g * 16 + q];
            }
            float gi = 1.f / (1.f + __expf(-zg4[0]));
            float gf = 1.f / (1.f + __expf(-zg4[1]));
            float gg = zg4[2] / (1.f + __expf(-zg4[2]));   // swish
            float go = 1.f / (1.f + __expf(-zg4[3]));
            float cv = gf * cbuf[tid] + gi * gg;
            cbuf[tid] = cv;
            float h  = go * (cv / (1.f + __expf(-cv)));    // o * swish(c)
            h_keep = h;                                     // out store deferred

            // pack bf16 pair via shfl; even-q lanes store one dword
            unsigned short hu = __builtin_bit_cast(unsigned short, (__bf16)h);
            int other = __shfl_xor((int)hu, 1);
            // J: poison (and out) stores drained before h lands at the LLC
            asm volatile("s_waitcnt vmcnt(0)" ::: "memory");
            if ((q & 1) == 0) {
                unsigned int packed = (unsigned int)hu | ((unsigned int)(unsigned short)other << 16);
                unsigned int* dst = (unsigned int*)(dirbase + (size_t)((t + 1) % 3) * 32768)
                                    + bb * 256 + ((colbase + q) >> 1);
                __hip_atomic_store(dst, packed, __ATOMIC_RELAXED, __HIP_MEMORY_SCOPE_AGENT);
            }
        }
        // no trailing barrier: hsb/xsb next written only after this iter's H;
        // zbuf next written only after F(t+1)
    }

    // final out store (t = T_STEPS-1)
    {
        const int txl = dir ? 0 : (T_STEPS - 1);
        out[(size_t)bb * (T_STEPS * 2 * UDIM) + (size_t)txl * (2 * UDIM)
            + dir * UDIM + colbase + q] = h_keep;
    }
}

extern "C" void kernel_launch(void* const* d_in, const int* in_sizes, int n_in,
                              void* d_out, int out_size, void* d_ws, size_t ws_size,
                              hipStream_t stream) {
    (void)in_sizes; (void)n_in; (void)out_size; (void)ws_size;
    const float* x  = (const float*)d_in[0];
    const float* Kf = (const float*)d_in[1];
    const float* Rf = (const float*)d_in[2];
    const float* bf = (const float*)d_in[3];
    const float* Kb = (const float*)d_in[4];
    const float* Rb = (const float*)d_in[5];
    const float* bb = (const float*)d_in[6];
    float* out = (float*)d_out;
    float* ws  = (float*)d_ws;

    void* args[] = {&x, &Kf, &Rf, &bf, &Kb, &Rb, &bb, &out, &ws};
    hipLaunchCooperativeKernel((const void*)lstm_bidir_kernel,
                               dim3(64), dim3(512), args, 0, stream);
}